// Round 8
// baseline (140.589 us; speedup 1.0000x reference)
//
#include <hip/hip_runtime.h>

typedef __attribute__((ext_vector_type(8))) short short8;
typedef __attribute__((ext_vector_type(4))) float f32x4;
typedef unsigned short u16;

__device__ __forceinline__ u16 f2bf(float f) {
    unsigned u = __builtin_bit_cast(unsigned, f);
    u += 0x7fffu + ((u >> 16) & 1u);
    return (u16)(u >> 16);
}
__device__ __forceinline__ float bf2f(u16 h) {
    return __builtin_bit_cast(float, (unsigned)h << 16);
}

// async global->LDS, 16B per lane; LDS dest = wave-uniform base + lane*16
#define GLDS(G, LBYTE)                                                         \
    __builtin_amdgcn_global_load_lds(                                          \
        (const __attribute__((address_space(1))) void*)(G),                    \
        (__attribute__((address_space(3))) void*)((char*)lds + (LBYTE)),       \
        16, 0, 0)

// wait until at most N vmem ops outstanding (counted, never drain in-loop)
#define WAITV6() asm volatile("s_waitcnt vmcnt(6)" ::: "memory")
#define WAITV0() asm volatile("s_waitcnt vmcnt(0)" ::: "memory")

// NT GEMM: C[m,n] = sum_k A[m,k]*B[n,k]  (A:[M,K] bf16(+lo), B:[N,K] bf16(+lo))
// 128x64 tile, 256 threads = 4 waves (2x2 of 64x32 each, acc 4x2).
// TRIPLE-buffered LDS with COUNTED vmcnt pipeline (T3/T4):
//   prologue: stage(tile0), stage(tile1)            -> 12 loads in flight
//   step t:   s_waitcnt vmcnt(6)  (oldest tile done, next 6 stay in flight)
//             s_barrier
//             stage(tile t+2)                        -> back to 12 in flight
//             compute(tile t)
//   tail:     vmcnt(0) on the last step only.
// One raw s_barrier per step; no vmcnt(0) drain in the main loop — loads span
// barriers (the m201/AITER discipline; __syncthreads would force a drain).
// LDS rows are 128B (8 x 16B slots), XOR-swizzled slot ^= row&7 (0-conflict,
// measured r4/r7). SPLIT: BK=32, row = [hi k0..31 | lo k0..31]; staging
// source selects plane per lane. non-split: BK=64. Swizzle via pre-swizzled
// GLOBAL source + same XOR on read (LDS dest of global_load_lds stays linear).
// XCD-aware bijective block swizzle: 1D grid, contiguous chunk per XCD.
// OUT: 0 = fp32, 1 = bf16, 2 = bf16 hi+lo pair (Cv=hi plane, C2=lo plane).
template<bool SPLIT, int OUT, bool BIAS, bool RELU, int GX, int GY>
__global__ __launch_bounds__(256, 2)
void gemm_nt(const u16* __restrict__ Ah, const u16* __restrict__ Al,
             const u16* __restrict__ Bh, const u16* __restrict__ Bl,
             const float* __restrict__ bias,
             void* __restrict__ Cv, u16* __restrict__ C2,
             int K, int lda, int ldb, int ldc,
             long sA, long sB, long sC)
{
    __shared__ u16 lds[36864];   // 72KB = 3 buffers x 24KB
    constexpr int BK  = SPLIT ? 32 : 64;  // K advance per step
    constexpr int BOF = 8192;             // B section offset (u16): A = 16KB

    // ---- XCD-aware bijective block swizzle (nwg % 8 == 0 for all our grids)
    const unsigned flat = blockIdx.x;
    const unsigned cpx  = gridDim.x >> 3;
    const unsigned id   = (flat & 7u) * cpx + (flat >> 3);
    const int bz  = (int)(id / (unsigned)(GX * GY));
    const int rem = (int)(id - (unsigned)bz * (GX * GY));
    const int by  = rem / GX;
    const int bx  = rem - by * GX;

    const int tid  = threadIdx.x;
    const int lane = tid & 63;
    const int wid  = tid >> 6;
    const int m0 = by * 128;
    const int n0 = bx * 64;

    // staging map: thread t -> chunk row t>>3 (32 rows of 128B per 4KB chunk),
    // logical slot sl = (t&7) ^ (row&7); linear LDS dest, swizzled global src.
    const int rowS = tid >> 3;                    // 0..31
    const int sl   = (tid & 7) ^ (rowS & 7);      // logical 16B slot
    const unsigned ldsW = (unsigned)wid * 1024u;  // wave base within 4KB chunk

    const u16 *aS, *bS;
    if constexpr (SPLIT) {
        // slot 0..3 -> hi plane cols (sl&3)*8 ; slot 4..7 -> lo plane
        aS = ((sl & 4) ? Al : Ah) + (size_t)bz * sA + ((size_t)m0 + rowS) * lda + (sl & 3) * 8;
        bS = ((sl & 4) ? Bl : Bh) + (size_t)bz * sB + ((size_t)n0 + rowS) * ldb + (sl & 3) * 8;
    } else {
        aS = Ah + (size_t)bz * sA + ((size_t)m0 + rowS) * lda + sl * 8;
        bS = Bh + (size_t)bz * sB + ((size_t)n0 + rowS) * ldb + sl * 8;
    }

    const int wm = (wid & 1) * 64;        // wave row in tile
    const int wn = (wid >> 1) * 32;       // wave col in tile
    const int fr = lane & 15;             // fragment row within 16
    const int fq = lane >> 4;             // fragment k-quad (0..3)

    f32x4 acc[4][2] = {};

    auto stage = [&](unsigned bb, int k0) {
        // A: 128 rows x 128B = 4 chunks; B: 64 rows x 128B = 2 chunks
        GLDS(aS + k0,            bb +     0 + ldsW);
        GLDS(aS + k0 + 32 * lda, bb +  4096 + ldsW);
        GLDS(aS + k0 + 64 * lda, bb +  8192 + ldsW);
        GLDS(aS + k0 + 96 * lda, bb + 12288 + ldsW);
        GLDS(bS + k0,            bb + 16384 + ldsW);
        GLDS(bS + k0 + 32 * ldb, bb + 20480 + ldsW);
    };

    auto compute = [&](unsigned be) {  // be = u16 element offset of buffer
        if constexpr (SPLIT) {
            const int swh = ((fq)     ^ (fr & 7)) << 3;   // hi slots 0..3
            const int swl = ((4 | fq) ^ (fr & 7)) << 3;   // lo slots 4..7
            short8 vah[4], vbh[2];
#pragma unroll
            for (int i = 0; i < 4; ++i)
                vah[i] = *(const short8*)(lds + be + (wm + i * 16 + fr) * 64 + swh);
#pragma unroll
            for (int j = 0; j < 2; ++j)
                vbh[j] = *(const short8*)(lds + be + BOF + (wn + j * 16 + fr) * 64 + swh);
#pragma unroll
            for (int i = 0; i < 4; ++i)
#pragma unroll
                for (int j = 0; j < 2; ++j)
                    acc[i][j] = __builtin_amdgcn_mfma_f32_16x16x32_bf16(vah[i], vbh[j], acc[i][j], 0, 0, 0);
            short8 val[4], vbl[2];
#pragma unroll
            for (int i = 0; i < 4; ++i)
                val[i] = *(const short8*)(lds + be + (wm + i * 16 + fr) * 64 + swl);
#pragma unroll
            for (int j = 0; j < 2; ++j)
                vbl[j] = *(const short8*)(lds + be + BOF + (wn + j * 16 + fr) * 64 + swl);
#pragma unroll
            for (int i = 0; i < 4; ++i)
#pragma unroll
                for (int j = 0; j < 2; ++j) {
                    acc[i][j] = __builtin_amdgcn_mfma_f32_16x16x32_bf16(vah[i], vbl[j], acc[i][j], 0, 0, 0);
                    acc[i][j] = __builtin_amdgcn_mfma_f32_16x16x32_bf16(val[i], vbh[j], acc[i][j], 0, 0, 0);
                }
        } else {
#pragma unroll
            for (int w = 0; w < 2; ++w) {
                const int sw = (((w << 2) | fq) ^ (fr & 7)) << 3;
                short8 vah[4], vbh[2];
#pragma unroll
                for (int i = 0; i < 4; ++i)
                    vah[i] = *(const short8*)(lds + be + (wm + i * 16 + fr) * 64 + sw);
#pragma unroll
                for (int j = 0; j < 2; ++j)
                    vbh[j] = *(const short8*)(lds + be + BOF + (wn + j * 16 + fr) * 64 + sw);
#pragma unroll
                for (int i = 0; i < 4; ++i)
#pragma unroll
                    for (int j = 0; j < 2; ++j)
                        acc[i][j] = __builtin_amdgcn_mfma_f32_16x16x32_bf16(vah[i], vbh[j], acc[i][j], 0, 0, 0);
            }
        }
    };

    // ---- counted-vmcnt 3-buffer pipeline (NT >= 3 for all our calls)
    const int NT = K / BK;
    stage(0u, 0);
    stage(24576u, BK);
    unsigned oA = 0u, oB = 24576u, oC = 49152u;   // byte offsets, rotate
    for (int t = 0; t < NT; ++t) {
        if (t + 1 < NT) { WAITV6(); } else { WAITV0(); }
        __builtin_amdgcn_s_barrier();
        if (t + 2 < NT) stage(oC, (t + 2) * BK);
        compute(oA >> 1);
        const unsigned tmp = oA; oA = oB; oB = oC; oC = tmp;
    }

    float bj[2];
    if (BIAS) {
#pragma unroll
        for (int j = 0; j < 2; ++j) bj[j] = bias[n0 + wn + j * 16 + fr];
    }
    const long crow0 = m0 + wm + fq * 4;
    const long ccol0 = n0 + wn + fr;
    float* Cf = (float*)Cv + (size_t)bz * sC;
    u16*   Cb = (u16*)Cv   + (size_t)bz * sC;
    u16*   Cl = (OUT == 2) ? (C2 + (size_t)bz * sC) : nullptr;
#pragma unroll
    for (int i = 0; i < 4; ++i)
#pragma unroll
        for (int j = 0; j < 2; ++j)
#pragma unroll
            for (int r = 0; r < 4; ++r) {
                float v = acc[i][j][r];
                if (BIAS) v += bj[j];
                if (RELU) v = fmaxf(v, 0.0f);
                const size_t idx = (size_t)(crow0 + i * 16 + r) * ldc + ccol0 + j * 16;
                if (OUT == 0) Cf[idx] = v;
                else if (OUT == 1) Cb[idx] = f2bf(v);
                else {
                    u16 h = f2bf(v);
                    Cb[idx] = h;
                    Cl[idx] = f2bf(v - bf2f(h));
                }
            }
}

// fp32 -> (hi bf16, lo bf16) planes, vectorized
__global__ __launch_bounds__(256)
void split_f32(const float* __restrict__ x, u16* __restrict__ hi,
               u16* __restrict__ lo, int n4)
{
    int i = blockIdx.x * 256 + threadIdx.x;
    const int stride = gridDim.x * 256;
    for (; i < n4; i += stride) {
        float4 v = ((const float4*)x)[i];
        ushort4 h, l;
        h.x = f2bf(v.x); l.x = f2bf(v.x - bf2f(h.x));
        h.y = f2bf(v.y); l.y = f2bf(v.y - bf2f(h.y));
        h.z = f2bf(v.z); l.z = f2bf(v.z - bf2f(h.z));
        h.w = f2bf(v.w); l.w = f2bf(v.w - bf2f(h.w));
        ((ushort4*)hi)[i] = h;
        ((ushort4*)lo)[i] = l;
    }
}

// per-batch transpose [512,768] fp32 -> [768,512] bf16
__global__ __launch_bounds__(256)
void transpose_to_bf16(const float* __restrict__ src, u16* __restrict__ dst)
{
    __shared__ u16 t[32][33];
    const int z = blockIdx.z;
    src += (size_t)z * 512 * 768;
    dst += (size_t)z * 768 * 512;
    const int h0 = blockIdx.x * 32;
    const int q0 = blockIdx.y * 32;
    const int tx = threadIdx.x;   // 0..31
    const int ty = threadIdx.y;   // 0..7
#pragma unroll
    for (int r = 0; r < 4; ++r)
        t[ty * 4 + r][tx] = f2bf(src[(size_t)(q0 + ty * 4 + r) * 768 + h0 + tx]);
    __syncthreads();
#pragma unroll
    for (int r = 0; r < 4; ++r)
        dst[(size_t)(h0 + ty * 4 + r) * 512 + q0 + tx] = t[tx][ty * 4 + r];
}

// MedLane masked softmax over 512 (fp32 in), writes bf16 probs in place
// (row stride stays 512 floats = 1024 bf16 elements)
__global__ __launch_bounds__(256)
void softmax_kernel(float* __restrict__ att, const int* __restrict__ seq_len)
{
    const int row = blockIdx.x;
    const int b   = row >> 9;
    float* s = att + (size_t)row * 512;
    const int L = seq_len[b];
    const int tid = threadIdx.x;

    __shared__ float red[4];

    const float v0 = s[tid];
    const float v1 = s[tid + 256];
    const float s0 = (tid < L) ? v0 : 0.0f;
    const float s1 = (tid + 256 < L) ? v1 : 0.0f;

    float m = fmaxf(s0, s1);
#pragma unroll
    for (int o = 32; o > 0; o >>= 1) m = fmaxf(m, __shfl_down(m, o));
    if ((tid & 63) == 0) red[tid >> 6] = m;
    __syncthreads();
    const float M = fmaxf(fmaxf(red[0], red[1]), fmaxf(red[2], red[3]));
    __syncthreads();

    const float e0 = expf(s0 - M);
    const float e1 = expf(s1 - M);

    float zs = e0 + e1;
#pragma unroll
    for (int o = 32; o > 0; o >>= 1) zs += __shfl_down(zs, o);
    if ((tid & 63) == 0) red[tid >> 6] = zs;
    __syncthreads();
    const float Z = red[0] + red[1] + red[2] + red[3];
    __syncthreads();

    const float p0 = (tid < L)       ? e0 / Z : 0.0f;
    const float p1 = (tid + 256 < L) ? e1 / Z : 0.0f;

    float ss = p0 + p1;
#pragma unroll
    for (int o = 32; o > 0; o >>= 1) ss += __shfl_down(ss, o);
    if ((tid & 63) == 0) red[tid >> 6] = ss;
    __syncthreads();
    const float S = red[0] + red[1] + red[2] + red[3];

    const float inv = 1.0f / (S + 1e-13f);
    u16* o16 = (u16*)s;
    o16[tid]       = f2bf(p0 * inv);
    o16[tid + 256] = f2bf(p1 * inv);
}

extern "C" void kernel_launch(void* const* d_in, const int* in_sizes, int n_in,
                              void* d_out, int out_size, void* d_ws, size_t ws_size,
                              hipStream_t stream)
{
    (void)in_sizes; (void)n_in; (void)out_size; (void)ws_size;
    constexpr int B = 16, L = 512, H = 768;
    constexpr size_t NPQ = (size_t)B * L * H;   // 6291456
    constexpr size_t NW  = (size_t)H * H;       // 589824

    const float* proj_p  = (const float*)d_in[0];
    const float* proj_q  = (const float*)d_in[1];
    const int*   seq_len = (const int*)d_in[2];
    const float* W       = (const float*)d_in[3];
    const float* bias    = (const float*)d_in[4];
    float* out = (float*)d_out;

    // workspace (u16 elements)
    u16* ws   = (u16*)d_ws;
    u16* Ah   = ws;                 // pq split, then pp split; later att_vec bf16
    u16* Al   = Ah + NPQ;
    u16* Wh   = Al + NPQ;
    u16* Wl   = Wh + NW;
    u16* pqT  = Wl + NW;            // [B,768,512] bf16
    float* att = (float*)(pqT + NPQ);  // [B,512,512] fp32 -> probs bf16 in place
    u16* att_vec = Ah;              // alias (pp split dead after GEMM2)

    // trans_q hi/lo planes live in d_out (exactly fills it), dead before GEMM5 writes
    u16* tq_hi = (u16*)d_out;
    u16* tq_lo = tq_hi + NPQ;

    // 1) splits + transposed bf16 proj_q
    split_f32<<<576, 256, 0, stream>>>(W, Wh, Wl, (int)(NW / 4));
    split_f32<<<2048, 256, 0, stream>>>(proj_q, Ah, Al, (int)(NPQ / 4));
    transpose_to_bf16<<<dim3(24, 16, 16), dim3(32, 8), 0, stream>>>(proj_q, pqT);

    // 2) trans_q = pq @ W^T + bias  (split in, split out)  grid 12x64 = 768
    gemm_nt<true, 2, true, false, 12, 64><<<768, 256, 0, stream>>>(
        Ah, Al, Wh, Wl, bias, tq_hi, tq_lo, H, H, H, H, 0, 0, 0);

    // 3) pp split (reuse Ah/Al)
    split_f32<<<2048, 256, 0, stream>>>(proj_p, Ah, Al, (int)(NPQ / 4));

    // 4) att[b] = pp[b] @ trans_q[b]^T  (split in, fp32 out)  grid 8x4x16 = 512
    gemm_nt<true, 0, false, false, 8, 4><<<512, 256, 0, stream>>>(
        Ah, Al, tq_hi, tq_lo, nullptr, att, nullptr, H, H, H, L,
        (long)L * H, (long)L * H, (long)L * L);

    // 5) masked softmax, bf16 probs in place (lda = 1024 u16)
    softmax_kernel<<<B * L, 256, 0, stream>>>(att, seq_len);

    // 6) att_vec[b] = probs[b] @ pqT[b]^T  (bf16, bf16 out)  grid 12x4x16 = 768
    gemm_nt<false, 1, false, false, 12, 4><<<768, 256, 0, stream>>>(
        (const u16*)att, nullptr, pqT, nullptr, nullptr, att_vec, nullptr,
        L, 1024, L, H, (long)L * 1024, (long)H * L, (long)L * H);

    // 7) out = relu(att_vec @ W^T + bias)  (bf16 in, fp32 out)  grid 12x64 = 768
    gemm_nt<false, 0, true, true, 12, 64><<<768, 256, 0, stream>>>(
        att_vec, nullptr, Wh, nullptr, bias, out, nullptr, H, H, H, H, 0, 0, 0);
}

// Round 9
// 97.039 us; speedup vs baseline: 1.4488x; 1.4488x over previous
//
#include <hip/hip_runtime.h>

typedef _Float16 f16x8 __attribute__((ext_vector_type(8)));
typedef __attribute__((ext_vector_type(4))) float f32x4;
typedef unsigned short u16;

__device__ __forceinline__ u16 f2h(float f) {
    _Float16 h = (_Float16)f;
    return __builtin_bit_cast(u16, h);
}

// async global->LDS, 16B per lane; LDS dest = wave-uniform base + lane*16
#define GLDS(G, LBYTE)                                                         \
    __builtin_amdgcn_global_load_lds(                                          \
        (const __attribute__((address_space(1))) void*)(G),                    \
        (__attribute__((address_space(3))) void*)((char*)lds + (LBYTE)),       \
        16, 0, 0)

// NT GEMM, fp16 inputs: C[m,n] = sum_k A[m,k]*B[n,k]   (A:[M,K], B:[N,K] fp16)
// 128x64 tile, BK=64, 256 threads = 4 waves (2x2 of 64x32 each, acc 4x2).
// fp32 accumulate via v_mfma_f32_16x16x32_f16.
// Double-buffered LDS, 2-phase pipeline (r7 structure — best measured):
// STAGE(next) issued BEFORE compute(cur), one __syncthreads() per step.
// LDS rows 128B (8 x 16B slots), XOR-swizzled slot ^= row&7 — measured
// 0-conflict (r4/r7). Swizzle via pre-swizzled GLOBAL source + same XOR on
// read; LDS dest of global_load_lds stays linear (both-sides-or-neither).
// XCD-aware bijective block swizzle: 1D grid, contiguous chunk per XCD.
// OUT: 0 = fp32, 1 = fp16.
template<int OUT, bool BIAS, bool RELU, int GX, int GY>
__global__ __launch_bounds__(256, 3)
void gemm_nt(const u16* __restrict__ A, const u16* __restrict__ B,
             const float* __restrict__ bias,
             void* __restrict__ Cv,
             int K, int lda, int ldb, int ldc,
             long sA, long sB, long sC)
{
    __shared__ u16 lds[24576];   // 48KB = 2 buffers x 24KB
    constexpr int BOF  = 8192;   // B section offset (u16): A = 16KB
    constexpr int BUFB = 24576;  // buffer stride (bytes)
    constexpr int BUFE = 12288;  // buffer stride (u16)

    // ---- XCD-aware bijective block swizzle (nwg % 8 == 0 for all our grids)
    const unsigned flat = blockIdx.x;
    const unsigned cpx  = gridDim.x >> 3;
    const unsigned id   = (flat & 7u) * cpx + (flat >> 3);
    const int bz  = (int)(id / (unsigned)(GX * GY));
    const int rem = (int)(id - (unsigned)bz * (GX * GY));
    const int by  = rem / GX;
    const int bx  = rem - by * GX;

    const int tid  = threadIdx.x;
    const int lane = tid & 63;
    const int wid  = tid >> 6;
    const int m0 = by * 128;
    const int n0 = bx * 64;

    // staging map: thread t -> chunk row t>>3 (32 rows of 128B per 4KB chunk),
    // logical slot sl = (t&7) ^ (row&7); linear LDS dest, swizzled global src.
    const int rowS = tid >> 3;                    // 0..31
    const int sl   = (tid & 7) ^ (rowS & 7);      // logical 16B slot
    const unsigned ldsW = (unsigned)wid * 1024u;  // wave base within 4KB chunk

    const u16* aS = A + (size_t)bz * sA + ((size_t)m0 + rowS) * lda + sl * 8;
    const u16* bS = B + (size_t)bz * sB + ((size_t)n0 + rowS) * ldb + sl * 8;

    const int wm = (wid & 1) * 64;        // wave row in tile
    const int wn = (wid >> 1) * 32;       // wave col in tile
    const int fr = lane & 15;             // fragment row within 16
    const int fq = lane >> 4;             // fragment k-quad (0..3)

    f32x4 acc[4][2] = {};

    auto stage = [&](int bb, int k0) {
        // A: 128 rows x 128B = 4 chunks; B: 64 rows x 128B = 2 chunks
        GLDS(aS + k0,            bb +     0 + ldsW);
        GLDS(aS + k0 + 32 * lda, bb +  4096 + ldsW);
        GLDS(aS + k0 + 64 * lda, bb +  8192 + ldsW);
        GLDS(aS + k0 + 96 * lda, bb + 12288 + ldsW);
        GLDS(bS + k0,            bb + 16384 + ldsW);
        GLDS(bS + k0 + 32 * ldb, bb + 20480 + ldsW);
    };

    auto compute = [&](int be) {  // be = u16 element offset of buffer
#pragma unroll
        for (int w = 0; w < 2; ++w) {
            const int sw = (((w << 2) | fq) ^ (fr & 7)) << 3;
            f16x8 vah[4], vbh[2];
#pragma unroll
            for (int i = 0; i < 4; ++i)
                vah[i] = *(const f16x8*)(lds + be + (wm + i * 16 + fr) * 64 + sw);
#pragma unroll
            for (int j = 0; j < 2; ++j)
                vbh[j] = *(const f16x8*)(lds + be + BOF + (wn + j * 16 + fr) * 64 + sw);
#pragma unroll
            for (int i = 0; i < 4; ++i)
#pragma unroll
                for (int j = 0; j < 2; ++j)
                    acc[i][j] = __builtin_amdgcn_mfma_f32_16x16x32_f16(vah[i], vbh[j], acc[i][j], 0, 0, 0);
        }
    };

    // ---- 2-phase pipelined K-loop (K is a multiple of 128 for all calls)
    stage(0, 0);
    __syncthreads();                       // vmcnt(0) drain: buf0 ready
    for (int k0 = 0; k0 < K; k0 += 128) {
        if (k0 + 64 < K) stage(BUFB, k0 + 64);   // prefetch into buf1
        compute(0);                               // compute buf0
        __syncthreads();                          // buf1 ready; buf0 free
        if (k0 + 128 < K) stage(0, k0 + 128);
        compute(BUFE);                            // compute buf1
        __syncthreads();
    }

    float bj[2];
    if (BIAS) {
#pragma unroll
        for (int j = 0; j < 2; ++j) bj[j] = bias[n0 + wn + j * 16 + fr];
    }
    const long crow0 = m0 + wm + fq * 4;
    const long ccol0 = n0 + wn + fr;
    float* Cf = (float*)Cv + (size_t)bz * sC;
    u16*   Ch = (u16*)Cv   + (size_t)bz * sC;
#pragma unroll
    for (int i = 0; i < 4; ++i)
#pragma unroll
        for (int j = 0; j < 2; ++j)
#pragma unroll
            for (int r = 0; r < 4; ++r) {
                float v = acc[i][j][r];
                if (BIAS) v += bj[j];
                if (RELU) v = fmaxf(v, 0.0f);
                const size_t idx = (size_t)(crow0 + i * 16 + r) * ldc + ccol0 + j * 16;
                if (OUT == 0) Cf[idx] = v;
                else          Ch[idx] = f2h(v);
            }
}

// fp32 -> fp16, vectorized
__global__ __launch_bounds__(256)
void cvt_f32_f16(const float* __restrict__ x, u16* __restrict__ y, int n4)
{
    int i = blockIdx.x * 256 + threadIdx.x;
    const int stride = gridDim.x * 256;
    for (; i < n4; i += stride) {
        float4 v = ((const float4*)x)[i];
        ushort4 h;
        h.x = f2h(v.x); h.y = f2h(v.y); h.z = f2h(v.z); h.w = f2h(v.w);
        ((ushort4*)y)[i] = h;
    }
}

// per-batch transpose [512,768] fp32 -> [768,512] fp16
__global__ __launch_bounds__(256)
void transpose_to_f16(const float* __restrict__ src, u16* __restrict__ dst)
{
    __shared__ u16 t[32][33];
    const int z = blockIdx.z;
    src += (size_t)z * 512 * 768;
    dst += (size_t)z * 768 * 512;
    const int h0 = blockIdx.x * 32;
    const int q0 = blockIdx.y * 32;
    const int tx = threadIdx.x;   // 0..31
    const int ty = threadIdx.y;   // 0..7
#pragma unroll
    for (int r = 0; r < 4; ++r)
        t[ty * 4 + r][tx] = f2h(src[(size_t)(q0 + ty * 4 + r) * 768 + h0 + tx]);
    __syncthreads();
#pragma unroll
    for (int r = 0; r < 4; ++r)
        dst[(size_t)(h0 + ty * 4 + r) * 512 + q0 + tx] = t[tx][ty * 4 + r];
}

// MedLane masked softmax over 512 (fp32 in), writes fp16 probs in place
// (row stride stays 512 floats = 1024 u16 elements)
__global__ __launch_bounds__(256)
void softmax_kernel(float* __restrict__ att, const int* __restrict__ seq_len)
{
    const int row = blockIdx.x;
    const int b   = row >> 9;
    float* s = att + (size_t)row * 512;
    const int L = seq_len[b];
    const int tid = threadIdx.x;

    __shared__ float red[4];

    const float v0 = s[tid];
    const float v1 = s[tid + 256];
    const float s0 = (tid < L) ? v0 : 0.0f;
    const float s1 = (tid + 256 < L) ? v1 : 0.0f;

    float m = fmaxf(s0, s1);
#pragma unroll
    for (int o = 32; o > 0; o >>= 1) m = fmaxf(m, __shfl_down(m, o));
    if ((tid & 63) == 0) red[tid >> 6] = m;
    __syncthreads();
    const float M = fmaxf(fmaxf(red[0], red[1]), fmaxf(red[2], red[3]));
    __syncthreads();

    const float e0 = expf(s0 - M);
    const float e1 = expf(s1 - M);

    float zs = e0 + e1;
#pragma unroll
    for (int o = 32; o > 0; o >>= 1) zs += __shfl_down(zs, o);
    if ((tid & 63) == 0) red[tid >> 6] = zs;
    __syncthreads();
    const float Z = red[0] + red[1] + red[2] + red[3];
    __syncthreads();

    const float p0 = (tid < L)       ? e0 / Z : 0.0f;
    const float p1 = (tid + 256 < L) ? e1 / Z : 0.0f;

    float ss = p0 + p1;
#pragma unroll
    for (int o = 32; o > 0; o >>= 1) ss += __shfl_down(ss, o);
    if ((tid & 63) == 0) red[tid >> 6] = ss;
    __syncthreads();
    const float S = red[0] + red[1] + red[2] + red[3];

    const float inv = 1.0f / (S + 1e-13f);
    u16* o16 = (u16*)s;
    o16[tid]       = f2h(p0 * inv);
    o16[tid + 256] = f2h(p1 * inv);
}

extern "C" void kernel_launch(void* const* d_in, const int* in_sizes, int n_in,
                              void* d_out, int out_size, void* d_ws, size_t ws_size,
                              hipStream_t stream)
{
    (void)in_sizes; (void)n_in; (void)out_size; (void)ws_size;
    constexpr int B = 16, L = 512, H = 768;
    constexpr size_t NPQ = (size_t)B * L * H;   // 6291456
    constexpr size_t NW  = (size_t)H * H;       // 589824

    const float* proj_p  = (const float*)d_in[0];
    const float* proj_q  = (const float*)d_in[1];
    const int*   seq_len = (const int*)d_in[2];
    const float* W       = (const float*)d_in[3];
    const float* bias    = (const float*)d_in[4];
    float* out = (float*)d_out;

    // workspace (u16 elements): pq16 | pp16 (-> av16 later) | W16 | pqT | att
    u16* ws   = (u16*)d_ws;
    u16* pq16 = ws;                    // [B,512,768] fp16
    u16* pp16 = pq16 + NPQ;            // [B,512,768] fp16; later av16
    u16* W16  = pp16 + NPQ;            // [768,768] fp16
    u16* pqT  = W16 + NW;              // [B,768,512] fp16
    float* att = (float*)(pqT + NPQ);  // [B,512,512] fp32 -> probs fp16 in place
    u16* av16 = pp16;                  // alias (pp16 dead after GEMM2)

    // trans_q fp16 lives in d_out's first half (dead before GEMM5 writes out)
    u16* tq16 = (u16*)d_out;

    // 1) fp16 conversions + transposed fp16 proj_q
    cvt_f32_f16<<<576, 256, 0, stream>>>(W, W16, (int)(NW / 4));
    cvt_f32_f16<<<2048, 256, 0, stream>>>(proj_q, pq16, (int)(NPQ / 4));
    cvt_f32_f16<<<2048, 256, 0, stream>>>(proj_p, pp16, (int)(NPQ / 4));
    transpose_to_f16<<<dim3(24, 16, 16), dim3(32, 8), 0, stream>>>(proj_q, pqT);

    // 2) tq16 = pq @ W^T + bias  (fp16 out)  grid 12x64 = 768
    gemm_nt<1, true, false, 12, 64><<<768, 256, 0, stream>>>(
        pq16, W16, bias, tq16, H, H, H, H, 0, 0, 0);

    // 3) att[b] = pp[b] @ tq[b]^T  (fp32 out)  grid 8x4x16 = 512
    gemm_nt<0, false, false, 8, 4><<<512, 256, 0, stream>>>(
        pp16, tq16, nullptr, att, H, H, H, L,
        (long)L * H, (long)L * H, (long)L * L);

    // 4) masked softmax, fp16 probs in place (lda = 1024 u16)
    softmax_kernel<<<B * L, 256, 0, stream>>>(att, seq_len);

    // 5) av16[b] = probs[b] @ pqT[b]^T  (fp16 out)  grid 12x4x16 = 768
    gemm_nt<1, false, false, 12, 4><<<768, 256, 0, stream>>>(
        (const u16*)att, pqT, nullptr, av16,
        L, 1024, L, H, (long)L * 1024, (long)H * L, (long)L * H);

    // 6) out = relu(av @ W^T + bias)  (fp32 out)  grid 12x64 = 768
    gemm_nt<0, true, true, 12, 64><<<768, 256, 0, stream>>>(
        av16, W16, bias, out, H, H, H, H, 0, 0, 0);
}

// Round 10
// 80.311 us; speedup vs baseline: 1.7506x; 1.2083x over previous
//
#include <hip/hip_runtime.h>

typedef _Float16 f16x8 __attribute__((ext_vector_type(8)));
typedef __attribute__((ext_vector_type(4))) float f32x4;
typedef unsigned short u16;

__device__ __forceinline__ u16 f2h(float f) {
    _Float16 h = (_Float16)f;
    return __builtin_bit_cast(u16, h);
}

// async global->LDS, 16B per lane; LDS dest = wave-uniform base + lane*16
#define GLDS(G, LBYTE)                                                         \
    __builtin_amdgcn_global_load_lds(                                          \
        (const __attribute__((address_space(1))) void*)(G),                    \
        (__attribute__((address_space(3))) void*)((char*)lds + (LBYTE)),       \
        16, 0, 0)

// NT GEMM, fp16 inputs: C[m,n] = sum_k A[m,k]*B[n,k]   (A:[M,K], B:[N,K] fp16)
// 128x64 tile, BK=64, 256 threads = 4 waves (2x2 of 64x32 each, acc 4x2).
// fp32 accumulate via v_mfma_f32_16x16x32_f16.
// Double-buffered LDS, 2-phase pipeline (r7/r9 structure — best measured):
// STAGE(next) issued BEFORE compute(cur), one __syncthreads() per step.
// LDS rows 128B (8 x 16B slots), XOR-swizzled slot ^= row&7 — measured
// 0-conflict (r4/r7). Swizzle via pre-swizzled GLOBAL source + same XOR on
// read; LDS dest of global_load_lds stays linear (both-sides-or-neither).
// XCD-aware bijective block swizzle: 1D grid, contiguous chunk per XCD.
// OUT: 0 = fp32, 1 = fp16.
// RS: epilogue v = acc + bias[n]*(1 - rs[row])  (fused trans-linear identity:
//     out = probs@tq + b*(1-sum(probs)); rs indexed per batch row).
template<int OUT, bool BIAS, bool RELU, bool RS, int GX, int GY>
__global__ __launch_bounds__(256, 3)
void gemm_nt(const u16* __restrict__ A, const u16* __restrict__ B,
             const float* __restrict__ bias, const float* __restrict__ rs,
             void* __restrict__ Cv,
             int K, int lda, int ldb, int ldc,
             long sA, long sB, long sC)
{
    __shared__ u16 lds[24576];   // 48KB = 2 buffers x 24KB
    constexpr int BOF  = 8192;   // B section offset (u16): A = 16KB
    constexpr int BUFB = 24576;  // buffer stride (bytes)
    constexpr int BUFE = 12288;  // buffer stride (u16)

    // ---- XCD-aware bijective block swizzle (nwg % 8 == 0 for all our grids)
    const unsigned flat = blockIdx.x;
    const unsigned cpx  = gridDim.x >> 3;
    const unsigned id   = (flat & 7u) * cpx + (flat >> 3);
    const int bz  = (int)(id / (unsigned)(GX * GY));
    const int rem = (int)(id - (unsigned)bz * (GX * GY));
    const int by  = rem / GX;
    const int bx  = rem - by * GX;

    const int tid  = threadIdx.x;
    const int lane = tid & 63;
    const int wid  = tid >> 6;
    const int m0 = by * 128;
    const int n0 = bx * 64;

    // staging map: thread t -> chunk row t>>3 (32 rows of 128B per 4KB chunk),
    // logical slot sl = (t&7) ^ (row&7); linear LDS dest, swizzled global src.
    const int rowS = tid >> 3;                    // 0..31
    const int sl   = (tid & 7) ^ (rowS & 7);      // logical 16B slot
    const unsigned ldsW = (unsigned)wid * 1024u;  // wave base within 4KB chunk

    const u16* aS = A + (size_t)bz * sA + ((size_t)m0 + rowS) * lda + sl * 8;
    const u16* bS = B + (size_t)bz * sB + ((size_t)n0 + rowS) * ldb + sl * 8;

    const int wm = (wid & 1) * 64;        // wave row in tile
    const int wn = (wid >> 1) * 32;       // wave col in tile
    const int fr = lane & 15;             // fragment row within 16
    const int fq = lane >> 4;             // fragment k-quad (0..3)

    f32x4 acc[4][2] = {};

    auto stage = [&](int bb, int k0) {
        // A: 128 rows x 128B = 4 chunks; B: 64 rows x 128B = 2 chunks
        GLDS(aS + k0,            bb +     0 + ldsW);
        GLDS(aS + k0 + 32 * lda, bb +  4096 + ldsW);
        GLDS(aS + k0 + 64 * lda, bb +  8192 + ldsW);
        GLDS(aS + k0 + 96 * lda, bb + 12288 + ldsW);
        GLDS(bS + k0,            bb + 16384 + ldsW);
        GLDS(bS + k0 + 32 * ldb, bb + 20480 + ldsW);
    };

    auto compute = [&](int be) {  // be = u16 element offset of buffer
#pragma unroll
        for (int w = 0; w < 2; ++w) {
            const int sw = (((w << 2) | fq) ^ (fr & 7)) << 3;
            f16x8 vah[4], vbh[2];
#pragma unroll
            for (int i = 0; i < 4; ++i)
                vah[i] = *(const f16x8*)(lds + be + (wm + i * 16 + fr) * 64 + sw);
#pragma unroll
            for (int j = 0; j < 2; ++j)
                vbh[j] = *(const f16x8*)(lds + be + BOF + (wn + j * 16 + fr) * 64 + sw);
#pragma unroll
            for (int i = 0; i < 4; ++i)
#pragma unroll
                for (int j = 0; j < 2; ++j)
                    acc[i][j] = __builtin_amdgcn_mfma_f32_16x16x32_f16(vah[i], vbh[j], acc[i][j], 0, 0, 0);
        }
    };

    // ---- 2-phase pipelined K-loop (K is a multiple of 128 for all calls)
    stage(0, 0);
    __syncthreads();                       // vmcnt(0) drain: buf0 ready
    for (int k0 = 0; k0 < K; k0 += 128) {
        if (k0 + 64 < K) stage(BUFB, k0 + 64);   // prefetch into buf1
        compute(0);                               // compute buf0
        __syncthreads();                          // buf1 ready; buf0 free
        if (k0 + 128 < K) stage(0, k0 + 128);
        compute(BUFE);                            // compute buf1
        __syncthreads();
    }

    float bj[2];
    if (BIAS) {
#pragma unroll
        for (int j = 0; j < 2; ++j) bj[j] = bias[n0 + wn + j * 16 + fr];
    }
    const long crow0 = m0 + wm + fq * 4;
    const long ccol0 = n0 + wn + fr;
    float* Cf = (float*)Cv + (size_t)bz * sC;
    u16*   Ch = (u16*)Cv   + (size_t)bz * sC;
    const float* rsb = RS ? (rs + (size_t)bz * 512) : nullptr;
#pragma unroll
    for (int i = 0; i < 4; ++i) {
        float rsv[4];
        if (RS) {
#pragma unroll
            for (int r = 0; r < 4; ++r) rsv[r] = 1.0f - rsb[crow0 + i * 16 + r];
        }
#pragma unroll
        for (int j = 0; j < 2; ++j)
#pragma unroll
            for (int r = 0; r < 4; ++r) {
                float v = acc[i][j][r];
                if (BIAS) v += RS ? bj[j] * rsv[r] : bj[j];
                if (RELU) v = fmaxf(v, 0.0f);
                const size_t idx = (size_t)(crow0 + i * 16 + r) * ldc + ccol0 + j * 16;
                if (OUT == 0) Cf[idx] = v;
                else          Ch[idx] = f2h(v);
            }
    }
}

// two fp32 -> fp16 conversions in one launch (same element count)
__global__ __launch_bounds__(256)
void cvt2_f32_f16(const float* __restrict__ x0, u16* __restrict__ y0,
                  const float* __restrict__ x1, u16* __restrict__ y1, int n4)
{
    int i = blockIdx.x * 256 + threadIdx.x;
    const int stride = gridDim.x * 256;
    for (; i < n4; i += stride) {
        float4 v0 = ((const float4*)x0)[i];
        float4 v1 = ((const float4*)x1)[i];
        ushort4 h0, h1;
        h0.x = f2h(v0.x); h0.y = f2h(v0.y); h0.z = f2h(v0.z); h0.w = f2h(v0.w);
        h1.x = f2h(v1.x); h1.y = f2h(v1.y); h1.z = f2h(v1.z); h1.w = f2h(v1.w);
        ((ushort4*)y0)[i] = h0;
        ((ushort4*)y1)[i] = h1;
    }
}

// fp32 -> fp16, vectorized (for W)
__global__ __launch_bounds__(256)
void cvt_f32_f16(const float* __restrict__ x, u16* __restrict__ y, int n4)
{
    int i = blockIdx.x * 256 + threadIdx.x;
    const int stride = gridDim.x * 256;
    for (; i < n4; i += stride) {
        float4 v = ((const float4*)x)[i];
        ushort4 h;
        h.x = f2h(v.x); h.y = f2h(v.y); h.z = f2h(v.z); h.w = f2h(v.w);
        ((ushort4*)y)[i] = h;
    }
}

// per-batch transpose [512,768] fp16 -> [768,512] fp16
__global__ __launch_bounds__(256)
void transpose_f16(const u16* __restrict__ src, u16* __restrict__ dst)
{
    __shared__ u16 t[32][33];
    const int z = blockIdx.z;
    src += (size_t)z * 512 * 768;
    dst += (size_t)z * 768 * 512;
    const int h0 = blockIdx.x * 32;
    const int q0 = blockIdx.y * 32;
    const int tx = threadIdx.x;   // 0..31
    const int ty = threadIdx.y;   // 0..7
#pragma unroll
    for (int r = 0; r < 4; ++r)
        t[ty * 4 + r][tx] = src[(size_t)(q0 + ty * 4 + r) * 768 + h0 + tx];
    __syncthreads();
#pragma unroll
    for (int r = 0; r < 4; ++r)
        dst[(size_t)(h0 + ty * 4 + r) * 512 + q0 + tx] = t[tx][ty * 4 + r];
}

// MedLane masked softmax over 512 (fp32 in), writes fp16 probs in place
// (row stride stays 512 floats = 1024 u16 elements) + per-row sum of final
// probs rs[row] = S/(S+1e-13) for the fused trans-linear bias correction.
__global__ __launch_bounds__(256)
void softmax_kernel(float* __restrict__ att, const int* __restrict__ seq_len,
                    float* __restrict__ rsout)
{
    const int row = blockIdx.x;
    const int b   = row >> 9;
    float* s = att + (size_t)row * 512;
    const int L = seq_len[b];
    const int tid = threadIdx.x;

    __shared__ float red[4];

    const float v0 = s[tid];
    const float v1 = s[tid + 256];
    const float s0 = (tid < L) ? v0 : 0.0f;
    const float s1 = (tid + 256 < L) ? v1 : 0.0f;

    float m = fmaxf(s0, s1);
#pragma unroll
    for (int o = 32; o > 0; o >>= 1) m = fmaxf(m, __shfl_down(m, o));
    if ((tid & 63) == 0) red[tid >> 6] = m;
    __syncthreads();
    const float M = fmaxf(fmaxf(red[0], red[1]), fmaxf(red[2], red[3]));
    __syncthreads();

    const float e0 = expf(s0 - M);
    const float e1 = expf(s1 - M);

    float zs = e0 + e1;
#pragma unroll
    for (int o = 32; o > 0; o >>= 1) zs += __shfl_down(zs, o);
    if ((tid & 63) == 0) red[tid >> 6] = zs;
    __syncthreads();
    const float Z = red[0] + red[1] + red[2] + red[3];
    __syncthreads();

    const float p0 = (tid < L)       ? e0 / Z : 0.0f;
    const float p1 = (tid + 256 < L) ? e1 / Z : 0.0f;

    float ss = p0 + p1;
#pragma unroll
    for (int o = 32; o > 0; o >>= 1) ss += __shfl_down(ss, o);
    if ((tid & 63) == 0) red[tid >> 6] = ss;
    __syncthreads();
    const float S = red[0] + red[1] + red[2] + red[3];

    const float inv = 1.0f / (S + 1e-13f);
    u16* o16 = (u16*)s;
    o16[tid]       = f2h(p0 * inv);
    o16[tid + 256] = f2h(p1 * inv);
    if (tid == 0) rsout[row] = S * inv;   // sum of final probs
}

extern "C" void kernel_launch(void* const* d_in, const int* in_sizes, int n_in,
                              void* d_out, int out_size, void* d_ws, size_t ws_size,
                              hipStream_t stream)
{
    (void)in_sizes; (void)n_in; (void)out_size; (void)ws_size;
    constexpr int B = 16, L = 512, H = 768;
    constexpr size_t NPQ = (size_t)B * L * H;   // 6291456
    constexpr size_t NW  = (size_t)H * H;       // 589824

    const float* proj_p  = (const float*)d_in[0];
    const float* proj_q  = (const float*)d_in[1];
    const int*   seq_len = (const int*)d_in[2];
    const float* W       = (const float*)d_in[3];
    const float* bias    = (const float*)d_in[4];
    float* out = (float*)d_out;

    // workspace (u16 elements): pq16 | pp16 | W16 | tqT | att | rs
    u16* ws   = (u16*)d_ws;
    u16* pq16 = ws;                    // [B,512,768] fp16
    u16* pp16 = pq16 + NPQ;            // [B,512,768] fp16
    u16* W16  = pp16 + NPQ;            // [768,768] fp16
    u16* tqT  = W16 + NW;              // [B,768,512] fp16 (trans_q transposed)
    float* att = (float*)(tqT + NPQ);  // [B,512,512] fp32 -> probs fp16 in place
    float* rs  = att + (size_t)B * L * L;  // [B,512] fp32 row sums

    // trans_q fp16 lives in d_out's first half (dead before final GEMM writes)
    u16* tq16 = (u16*)d_out;

    // 1) fp16 conversions
    cvt_f32_f16<<<576, 256, 0, stream>>>(W, W16, (int)(NW / 4));
    cvt2_f32_f16<<<2048, 256, 0, stream>>>(proj_q, pq16, proj_p, pp16, (int)(NPQ / 4));

    // 2) tq16 = pq @ W^T + bias  (fp16 out)  grid 12x64 = 768
    gemm_nt<1, true, false, false, 12, 64><<<768, 256, 0, stream>>>(
        pq16, W16, bias, nullptr, tq16, H, H, H, H, 0, 0, 0);

    // 3) tqT[b] = tq16[b]^T  (for the fused output GEMM's B operand)
    transpose_f16<<<dim3(24, 16, 16), dim3(32, 8), 0, stream>>>(tq16, tqT);

    // 4) att[b] = pp[b] @ tq[b]^T  (fp32 out)  grid 8x4x16 = 512
    gemm_nt<0, false, false, false, 8, 4><<<512, 256, 0, stream>>>(
        pp16, tq16, nullptr, nullptr, att, H, H, H, L,
        (long)L * H, (long)L * H, (long)L * L);

    // 5) masked softmax, fp16 probs in place + rs
    softmax_kernel<<<B * L, 256, 0, stream>>>(att, seq_len, rs);

    // 6) out = relu(probs @ tqT^T + bias*(1-rs))   grid 12x4x16 = 768
    //    (algebraic fusion of att_vec GEMM + output trans_linear:
    //     (probs@pq)@W^T + b == probs@tq + b*(1-sum(probs)))
    gemm_nt<0, true, true, true, 12, 4><<<768, 256, 0, stream>>>(
        (const u16*)att, tqT, bias, rs, out,
        L, 1024, L, H, (long)L * 1024, (long)H * L, (long)L * H);
}

// Round 11
// 71.465 us; speedup vs baseline: 1.9672x; 1.1238x over previous
//
#include <hip/hip_runtime.h>

typedef _Float16 f16x8 __attribute__((ext_vector_type(8)));
typedef __attribute__((ext_vector_type(4))) float f32x4;
typedef unsigned short u16;

__device__ __forceinline__ u16 f2h(float f) {
    _Float16 h = (_Float16)f;
    return __builtin_bit_cast(u16, h);
}

// async global->LDS, 16B per lane; LDS dest = wave-uniform base + lane*16
#define GLDS(G, LBYTE)                                                         \
    __builtin_amdgcn_global_load_lds(                                          \
        (const __attribute__((address_space(1))) void*)(G),                    \
        (__attribute__((address_space(3))) void*)((char*)lds + (LBYTE)),       \
        16, 0, 0)

// NT GEMM, fp16 inputs: C[m,n] = sum_k A[m,k]*B[n,k]   (A:[M,K], B:[N,K] fp16)
// 128x64 tile, BK=64, 256 threads = 4 waves (2x2 of 64x32 each, acc 4x2).
// fp32 accumulate via v_mfma_f32_16x16x32_f16.
// Double-buffered LDS, 2-phase pipeline (r7/r9 structure — best measured):
// STAGE(next) issued BEFORE compute(cur), one __syncthreads() per step.
// LDS rows 128B (8 x 16B slots), XOR-swizzled slot ^= row&7 — measured
// 0-conflict (r4/r7). Swizzle via pre-swizzled GLOBAL source + same XOR on
// read; LDS dest of global_load_lds stays linear (both-sides-or-neither).
// XCD-aware bijective block swizzle: 1D grid, contiguous chunk per XCD.
// OUT: 0 = fp32, 1 = fp16.
// TW (requires OUT==1, M batched by 512): ALSO write C transposed per batch:
//     CT[b][n][q] (q = row within batch) — 4 consecutive q per ushort4 store.
//     This replaces the separate transpose kernel (values already in regs).
// RS: epilogue v = acc + bias[n]*(1 - rs[row])  (fused trans-linear identity:
//     out = probs@tq + b*(1-sum(probs)); rs indexed per batch row).
template<int OUT, bool BIAS, bool RELU, bool RS, bool TW, int GX, int GY>
__global__ __launch_bounds__(256, 3)
void gemm_nt(const u16* __restrict__ A, const u16* __restrict__ B,
             const float* __restrict__ bias, const float* __restrict__ rs,
             void* __restrict__ Cv, u16* __restrict__ CT,
             int K, int lda, int ldb, int ldc,
             long sA, long sB, long sC)
{
    __shared__ u16 lds[24576];   // 48KB = 2 buffers x 24KB
    constexpr int BOF  = 8192;   // B section offset (u16): A = 16KB
    constexpr int BUFB = 24576;  // buffer stride (bytes)
    constexpr int BUFE = 12288;  // buffer stride (u16)

    // ---- XCD-aware bijective block swizzle (nwg % 8 == 0 for all our grids)
    const unsigned flat = blockIdx.x;
    const unsigned cpx  = gridDim.x >> 3;
    const unsigned id   = (flat & 7u) * cpx + (flat >> 3);
    const int bz  = (int)(id / (unsigned)(GX * GY));
    const int rem = (int)(id - (unsigned)bz * (GX * GY));
    const int by  = rem / GX;
    const int bx  = rem - by * GX;

    const int tid  = threadIdx.x;
    const int lane = tid & 63;
    const int wid  = tid >> 6;
    const int m0 = by * 128;
    const int n0 = bx * 64;

    // staging map: thread t -> chunk row t>>3 (32 rows of 128B per 4KB chunk),
    // logical slot sl = (t&7) ^ (row&7); linear LDS dest, swizzled global src.
    const int rowS = tid >> 3;                    // 0..31
    const int sl   = (tid & 7) ^ (rowS & 7);      // logical 16B slot
    const unsigned ldsW = (unsigned)wid * 1024u;  // wave base within 4KB chunk

    const u16* aS = A + (size_t)bz * sA + ((size_t)m0 + rowS) * lda + sl * 8;
    const u16* bS = B + (size_t)bz * sB + ((size_t)n0 + rowS) * ldb + sl * 8;

    const int wm = (wid & 1) * 64;        // wave row in tile
    const int wn = (wid >> 1) * 32;       // wave col in tile
    const int fr = lane & 15;             // fragment row within 16
    const int fq = lane >> 4;             // fragment k-quad (0..3)

    f32x4 acc[4][2] = {};

    auto stage = [&](int bb, int k0) {
        // A: 128 rows x 128B = 4 chunks; B: 64 rows x 128B = 2 chunks
        GLDS(aS + k0,            bb +     0 + ldsW);
        GLDS(aS + k0 + 32 * lda, bb +  4096 + ldsW);
        GLDS(aS + k0 + 64 * lda, bb +  8192 + ldsW);
        GLDS(aS + k0 + 96 * lda, bb + 12288 + ldsW);
        GLDS(bS + k0,            bb + 16384 + ldsW);
        GLDS(bS + k0 + 32 * ldb, bb + 20480 + ldsW);
    };

    auto compute = [&](int be) {  // be = u16 element offset of buffer
#pragma unroll
        for (int w = 0; w < 2; ++w) {
            const int sw = (((w << 2) | fq) ^ (fr & 7)) << 3;
            f16x8 vah[4], vbh[2];
#pragma unroll
            for (int i = 0; i < 4; ++i)
                vah[i] = *(const f16x8*)(lds + be + (wm + i * 16 + fr) * 64 + sw);
#pragma unroll
            for (int j = 0; j < 2; ++j)
                vbh[j] = *(const f16x8*)(lds + be + BOF + (wn + j * 16 + fr) * 64 + sw);
#pragma unroll
            for (int i = 0; i < 4; ++i)
#pragma unroll
                for (int j = 0; j < 2; ++j)
                    acc[i][j] = __builtin_amdgcn_mfma_f32_16x16x32_f16(vah[i], vbh[j], acc[i][j], 0, 0, 0);
        }
    };

    // ---- 2-phase pipelined K-loop (K is a multiple of 128 for all calls)
    stage(0, 0);
    __syncthreads();                       // vmcnt(0) drain: buf0 ready
    for (int k0 = 0; k0 < K; k0 += 128) {
        if (k0 + 64 < K) stage(BUFB, k0 + 64);   // prefetch into buf1
        compute(0);                               // compute buf0
        __syncthreads();                          // buf1 ready; buf0 free
        if (k0 + 128 < K) stage(0, k0 + 128);
        compute(BUFE);                            // compute buf1
        __syncthreads();
    }

    float bj[2];
    if (BIAS) {
#pragma unroll
        for (int j = 0; j < 2; ++j) bj[j] = bias[n0 + wn + j * 16 + fr];
    }
    const long crow0 = m0 + wm + fq * 4;
    const long ccol0 = n0 + wn + fr;
    float* Cf = (float*)Cv + (size_t)bz * sC;
    u16*   Ch = (u16*)Cv   + (size_t)bz * sC;
    const float* rsb = RS ? (rs + (size_t)bz * 512) : nullptr;
    // TW: batch of this tile (M batched by 512; 128-tiles never straddle)
    const int  bzT = (int)(crow0 >> 9);
    const long qb  = crow0 & 511;
#pragma unroll
    for (int i = 0; i < 4; ++i) {
        float rsv[4];
        if (RS) {
#pragma unroll
            for (int r = 0; r < 4; ++r) rsv[r] = 1.0f - rsb[crow0 + i * 16 + r];
        }
#pragma unroll
        for (int j = 0; j < 2; ++j) {
            ushort4 tw;
#pragma unroll
            for (int r = 0; r < 4; ++r) {
                float v = acc[i][j][r];
                if (BIAS) v += RS ? bj[j] * rsv[r] : bj[j];
                if (RELU) v = fmaxf(v, 0.0f);
                const size_t idx = (size_t)(crow0 + i * 16 + r) * ldc + ccol0 + j * 16;
                if (OUT == 0) Cf[idx] = v;
                else {
                    const u16 h = f2h(v);
                    Ch[idx] = h;
                    if (TW) (&tw.x)[r] = h;
                }
            }
            if (OUT == 1 && TW) {
                // CT[bzT][ccol0 + j*16][qb + i*16 .. +3]
                *(ushort4*)(CT + (size_t)bzT * 768 * 512
                               + (size_t)(ccol0 + j * 16) * 512 + qb + i * 16) = tw;
            }
        }
    }
}

// fused fp32 -> fp16 conversions: pq, pp (n4 float4s each) and W (nW4 float4s)
__global__ __launch_bounds__(256)
void cvt_all(const float* __restrict__ x0, u16* __restrict__ y0,
             const float* __restrict__ x1, u16* __restrict__ y1, int n4,
             const float* __restrict__ xw, u16* __restrict__ yw, int nW4)
{
    int i = blockIdx.x * 256 + threadIdx.x;
    const int stride = gridDim.x * 256;
    for (; i < n4; i += stride) {
        float4 v0 = ((const float4*)x0)[i];
        float4 v1 = ((const float4*)x1)[i];
        ushort4 h0, h1;
        h0.x = f2h(v0.x); h0.y = f2h(v0.y); h0.z = f2h(v0.z); h0.w = f2h(v0.w);
        h1.x = f2h(v1.x); h1.y = f2h(v1.y); h1.z = f2h(v1.z); h1.w = f2h(v1.w);
        ((ushort4*)y0)[i] = h0;
        ((ushort4*)y1)[i] = h1;
        if (i < nW4) {
            float4 vw = ((const float4*)xw)[i];
            ushort4 hw;
            hw.x = f2h(vw.x); hw.y = f2h(vw.y); hw.z = f2h(vw.z); hw.w = f2h(vw.w);
            ((ushort4*)yw)[i] = hw;
        }
    }
}

// MedLane masked softmax over 512 (fp32 in), writes fp16 probs in place
// (row stride stays 512 floats = 1024 u16 elements) + rs[row] = S/(S+1e-13).
// 2 reductions only: masked entries contribute exactly exp(-M) each to Z, so
//   Z = sve + (512-L)*exp(-M),  S = sve/Z   (analytic; no third reduction).
__global__ __launch_bounds__(256)
void softmax_kernel(float* __restrict__ att, const int* __restrict__ seq_len,
                    float* __restrict__ rsout)
{
    const int row = blockIdx.x;
    const int b   = row >> 9;
    float* s = att + (size_t)row * 512;
    const int L = seq_len[b];
    const int tid = threadIdx.x;

    __shared__ float red[4];

    const float v0 = s[tid];
    const float v1 = s[tid + 256];
    const bool  k0 = (tid < L);
    const bool  k1 = (tid + 256 < L);
    const float s0 = k0 ? v0 : 0.0f;
    const float s1 = k1 ? v1 : 0.0f;

    float m = fmaxf(s0, s1);
#pragma unroll
    for (int o = 32; o > 0; o >>= 1) m = fmaxf(m, __shfl_down(m, o));
    if ((tid & 63) == 0) red[tid >> 6] = m;
    __syncthreads();
    const float M = fmaxf(fmaxf(red[0], red[1]), fmaxf(red[2], red[3]));
    __syncthreads();

    const float e0 = k0 ? expf(s0 - M) : 0.0f;
    const float e1 = k1 ? expf(s1 - M) : 0.0f;

    float zs = e0 + e1;
#pragma unroll
    for (int o = 32; o > 0; o >>= 1) zs += __shfl_down(zs, o);
    if ((tid & 63) == 0) red[tid >> 6] = zs;
    __syncthreads();
    const float sve = red[0] + red[1] + red[2] + red[3];

    const float Z   = sve + (float)(512 - L) * expf(-M);
    const float S   = sve / Z;
    const float inv = 1.0f / (S + 1e-13f);
    const float sc  = inv / Z;

    u16* o16 = (u16*)s;
    o16[tid]       = f2h(k0 ? e0 * sc : 0.0f);
    o16[tid + 256] = f2h(k1 ? e1 * sc : 0.0f);
    if (tid == 0) rsout[row] = S * inv;
}

extern "C" void kernel_launch(void* const* d_in, const int* in_sizes, int n_in,
                              void* d_out, int out_size, void* d_ws, size_t ws_size,
                              hipStream_t stream)
{
    (void)in_sizes; (void)n_in; (void)out_size; (void)ws_size;
    constexpr int B = 16, L = 512, H = 768;
    constexpr size_t NPQ = (size_t)B * L * H;   // 6291456
    constexpr size_t NW  = (size_t)H * H;       // 589824

    const float* proj_p  = (const float*)d_in[0];
    const float* proj_q  = (const float*)d_in[1];
    const int*   seq_len = (const int*)d_in[2];
    const float* W       = (const float*)d_in[3];
    const float* bias    = (const float*)d_in[4];
    float* out = (float*)d_out;

    // workspace (u16 elements): pq16 | pp16 | W16 | tqT | att | rs
    u16* ws   = (u16*)d_ws;
    u16* pq16 = ws;                    // [B,512,768] fp16
    u16* pp16 = pq16 + NPQ;            // [B,512,768] fp16
    u16* W16  = pp16 + NPQ;            // [768,768] fp16
    u16* tqT  = W16 + NW;              // [B,768,512] fp16 (trans_q transposed)
    float* att = (float*)(tqT + NPQ);  // [B,512,512] fp32 -> probs fp16 in place
    float* rs  = att + (size_t)B * L * L;  // [B,512] fp32 row sums

    // trans_q fp16 lives in d_out's first half (dead before final GEMM writes)
    u16* tq16 = (u16*)d_out;

    // 1) all fp16 conversions in one dispatch
    cvt_all<<<2048, 256, 0, stream>>>(proj_q, pq16, proj_p, pp16, (int)(NPQ / 4),
                                      W, W16, (int)(NW / 4));

    // 2) tq16 = pq @ W^T + bias  (fp16 out, dual row-major + transposed write)
    gemm_nt<1, true, false, false, true, 12, 64><<<768, 256, 0, stream>>>(
        pq16, W16, bias, nullptr, tq16, tqT, H, H, H, H, 0, 0, 0);

    // 3) att[b] = pp[b] @ tq[b]^T  (fp32 out)  grid 8x4x16 = 512
    gemm_nt<0, false, false, false, false, 8, 4><<<512, 256, 0, stream>>>(
        pp16, tq16, nullptr, nullptr, att, nullptr, H, H, H, L,
        (long)L * H, (long)L * H, (long)L * L);

    // 4) masked softmax (2-reduction), fp16 probs in place + rs
    softmax_kernel<<<B * L, 256, 0, stream>>>(att, seq_len, rs);

    // 5) out = relu(probs @ tqT^T + bias*(1-rs))   grid 12x4x16 = 768
    //    (algebraic fusion: (probs@pq)@W^T + b == probs@tq + b*(1-sum(probs)))
    gemm_nt<0, true, true, true, false, 12, 4><<<768, 256, 0, stream>>>(
        (const u16*)att, tqT, bias, rs, out, nullptr,
        L, 1024, L, H, (long)L * 1024, (long)H * L, (long)L * H);
}